// Round 5
// baseline (2587.895 us; speedup 1.0000x reference)
//
#include <hip/hip_runtime.h>
#include <math.h>

#define Nn    100000
#define Ee    3200000
#define NNZn  6400000
#define NF    (Nn * 16)     // floats per node-feature buffer
#define K     512           // row buckets
#define RPB   196           // rows per bucket = ceil(Nn/K)
#define CHUNK 16384         // items per binning block

__device__ __forceinline__ float bfu(unsigned int w) {        // low bf16 of w
  return __uint_as_float(w << 16);
}
__device__ __forceinline__ float bfh(unsigned int w) {        // high bf16 of w
  return __uint_as_float(w & 0xffff0000u);
}
__device__ __forceinline__ unsigned int f2bf(float f) {       // fp32->bf16 RNE
  unsigned int u = __float_as_uint(f);
  return (u + 0x7fffu + ((u >> 16) & 1u)) >> 16;
}

// ---------------------------------------------------------------------------
// Count: per-block LDS histogram of key/RPB, one global atomic per bucket.
// ---------------------------------------------------------------------------
__global__ __launch_bounds__(256) void count_kernel(
    const int* __restrict__ keys, int n, int* __restrict__ tot) {
  __shared__ int h[K];
  int t = threadIdx.x;
  for (int i = t; i < K; i += 256) h[i] = 0;
  __syncthreads();
  int base = blockIdx.x * CHUNK;
  int end = min(base + CHUNK, n);
  for (int i = base + t; i < end; i += 256) atomicAdd(&h[keys[i] / RPB], 1);
  __syncthreads();
  for (int i = t; i < K; i += 256)
    if (h[i]) atomicAdd(&tot[i], h[i]);
}

// ---------------------------------------------------------------------------
// Exclusive scan of bucket totals -> bucket_start + cursor. 2 blocks x K.
// ---------------------------------------------------------------------------
__global__ __launch_bounds__(K) void scan_kernel(
    const int* __restrict__ tot_e, const int* __restrict__ tot_p,
    int* __restrict__ bs_e, int* __restrict__ cur_e,
    int* __restrict__ bs_p, int* __restrict__ cur_p) {
  const int* tot = (blockIdx.x == 0) ? tot_e : tot_p;
  int* bs  = (blockIdx.x == 0) ? bs_e  : bs_p;
  int* cur = (blockIdx.x == 0) ? cur_e : cur_p;
  __shared__ int s[K];
  int t = threadIdx.x;
  s[t] = tot[t];
  __syncthreads();
  for (int off = 1; off < K; off <<= 1) {
    int v = (t >= off) ? s[t - off] : 0;
    __syncthreads();
    s[t] += v;
    __syncthreads();
  }
  int excl = t ? s[t - 1] : 0;
  bs[t] = excl;
  cur[t] = excl;
  if (t == K - 1) bs[K] = s[K - 1];
}

// ---------------------------------------------------------------------------
// Bin edges: binned_e[pos] = (local_row<<17) | src.
// ---------------------------------------------------------------------------
__global__ __launch_bounds__(256) void bin_edges(
    const int* __restrict__ dst, const int* __restrict__ src,
    int* __restrict__ cur, int* __restrict__ binned) {
  __shared__ int h[K];
  int t = threadIdx.x;
  for (int i = t; i < K; i += 256) h[i] = 0;
  __syncthreads();
  int base = blockIdx.x * CHUNK;
  int end = min(base + CHUNK, Ee);
  for (int i = base + t; i < end; i += 256) atomicAdd(&h[dst[i] / RPB], 1);
  __syncthreads();
  for (int k = t; k < K; k += 256) {
    int c = h[k];
    h[k] = c ? atomicAdd(&cur[k], c) : 0;
  }
  __syncthreads();
  for (int i = base + t; i < end; i += 256) {
    int d = dst[i];
    int k = d / RPB;
    int lr = d - k * RPB;
    int pos = atomicAdd(&h[k], 1);
    binned[pos] = (lr << 17) | src[i];
  }
}

// ---------------------------------------------------------------------------
// Bin pm: bp[pos] = { (local_row<<22)|col , bits(val) }
// ---------------------------------------------------------------------------
__global__ __launch_bounds__(256) void bin_pm(
    const int* __restrict__ rows, const int* __restrict__ cols,
    const float* __restrict__ vals,
    int* __restrict__ cur, int2* __restrict__ bp) {
  __shared__ int h[K];
  int t = threadIdx.x;
  for (int i = t; i < K; i += 256) h[i] = 0;
  __syncthreads();
  int base = blockIdx.x * CHUNK;
  int end = min(base + CHUNK, NNZn);
  for (int i = base + t; i < end; i += 256) atomicAdd(&h[rows[i] / RPB], 1);
  __syncthreads();
  for (int k = t; k < K; k += 256) {
    int c = h[k];
    h[k] = c ? atomicAdd(&cur[k], c) : 0;
  }
  __syncthreads();
  for (int i = base + t; i < end; i += 256) {
    int r = rows[i];
    int k = r / RPB;
    int lr = r - k * RPB;
    int pos = atomicAdd(&h[k], 1);
    bp[pos] = make_int2((lr << 22) | cols[i], __float_as_int(vals[i]));
  }
}

// ---------------------------------------------------------------------------
// fp32 -> bf16 row conversion (pairs packed in uint). n16 = #elements/2.
// ---------------------------------------------------------------------------
__global__ __launch_bounds__(256) void cvt_bf16(
    const float* __restrict__ in, unsigned int* __restrict__ out, int npair) {
  int i = blockIdx.x * 256 + threadIdx.x;
  if (i >= npair) return;
  float2 v = ((const float2*)in)[i];
  out[i] = f2bf(v.x) | (f2bf(v.y) << 16);
}

// ---------------------------------------------------------------------------
// Hop over one bucket, bf16 zin (uint-packed pairs), bf16 zout.
// 128 8-lane groups per 1024-thread block; lane owns features 2f2, 2f2+1.
// ---------------------------------------------------------------------------
__global__ __launch_bounds__(1024) void hop_bucket(
    const unsigned int* __restrict__ zin, unsigned int* __restrict__ zout,
    const int* __restrict__ binned, const int* __restrict__ bs) {
  __shared__ float acc[RPB * 17];
  int t = threadIdx.x;
  int b = blockIdx.x;
  for (int i = t; i < RPB * 17; i += 1024) acc[i] = 0.f;
  __syncthreads();
  int s0 = bs[b], s1 = bs[b + 1];
  int g = t >> 3, f2 = t & 7;
  int i = s0 + g;
  for (; i + 384 < s1; i += 512) {
    int p0 = binned[i];
    int p1 = binned[i + 128];
    int p2 = binned[i + 256];
    int p3 = binned[i + 384];
    unsigned int w0 = zin[(size_t)(p0 & 0x1FFFF) * 8 + f2];
    unsigned int w1 = zin[(size_t)(p1 & 0x1FFFF) * 8 + f2];
    unsigned int w2 = zin[(size_t)(p2 & 0x1FFFF) * 8 + f2];
    unsigned int w3 = zin[(size_t)(p3 & 0x1FFFF) * 8 + f2];
    int a0 = (p0 >> 17) * 17 + 2 * f2;
    int a1 = (p1 >> 17) * 17 + 2 * f2;
    int a2 = (p2 >> 17) * 17 + 2 * f2;
    int a3 = (p3 >> 17) * 17 + 2 * f2;
    atomicAdd(&acc[a0], bfu(w0)); atomicAdd(&acc[a0 + 1], bfh(w0));
    atomicAdd(&acc[a1], bfu(w1)); atomicAdd(&acc[a1 + 1], bfh(w1));
    atomicAdd(&acc[a2], bfu(w2)); atomicAdd(&acc[a2 + 1], bfh(w2));
    atomicAdd(&acc[a3], bfu(w3)); atomicAdd(&acc[a3 + 1], bfh(w3));
  }
  for (; i < s1; i += 128) {
    int p = binned[i];
    unsigned int w = zin[(size_t)(p & 0x1FFFF) * 8 + f2];
    int a = (p >> 17) * 17 + 2 * f2;
    atomicAdd(&acc[a], bfu(w));
    atomicAdd(&acc[a + 1], bfh(w));
  }
  __syncthreads();
  int r0 = b * RPB;
  int nr = min(RPB, Nn - r0);
  if (nr > 0)
    for (int j = t; j < nr * 8; j += 1024) {
      int row = j >> 3, c2 = j & 7;
      unsigned int lo = f2bf(acc[row * 17 + 2 * c2]);
      unsigned int hi = f2bf(acc[row * 17 + 2 * c2 + 1]);
      zout[(size_t)r0 * 8 + j] = lo | (hi << 16);
    }
}

// ---------------------------------------------------------------------------
// pm over one bucket, bf16 feat_b variant (uint-packed pairs).
// ---------------------------------------------------------------------------
__global__ __launch_bounds__(1024) void pm_bucket_bf(
    const unsigned int* __restrict__ fb16, const int2* __restrict__ bp,
    const int* __restrict__ bs, float* __restrict__ pm_y) {
  __shared__ float acc[RPB * 17];
  int t = threadIdx.x;
  int b = blockIdx.x;
  for (int i = t; i < RPB * 17; i += 1024) acc[i] = 0.f;
  __syncthreads();
  int s0 = bs[b], s1 = bs[b + 1];
  int g = t >> 3, f2 = t & 7;
  int i = s0 + g;
  for (; i + 384 < s1; i += 512) {
    int2 e0 = bp[i];
    int2 e1 = bp[i + 128];
    int2 e2 = bp[i + 256];
    int2 e3 = bp[i + 384];
    unsigned int w0 = fb16[(size_t)(e0.x & 0x3FFFFF) * 8 + f2];
    unsigned int w1 = fb16[(size_t)(e1.x & 0x3FFFFF) * 8 + f2];
    unsigned int w2 = fb16[(size_t)(e2.x & 0x3FFFFF) * 8 + f2];
    unsigned int w3 = fb16[(size_t)(e3.x & 0x3FFFFF) * 8 + f2];
    float v0 = __int_as_float(e0.y), v1 = __int_as_float(e1.y);
    float v2 = __int_as_float(e2.y), v3 = __int_as_float(e3.y);
    int a0 = ((unsigned)e0.x >> 22) * 17 + 2 * f2;
    int a1 = ((unsigned)e1.x >> 22) * 17 + 2 * f2;
    int a2 = ((unsigned)e2.x >> 22) * 17 + 2 * f2;
    int a3 = ((unsigned)e3.x >> 22) * 17 + 2 * f2;
    atomicAdd(&acc[a0], v0 * bfu(w0)); atomicAdd(&acc[a0 + 1], v0 * bfh(w0));
    atomicAdd(&acc[a1], v1 * bfu(w1)); atomicAdd(&acc[a1 + 1], v1 * bfh(w1));
    atomicAdd(&acc[a2], v2 * bfu(w2)); atomicAdd(&acc[a2 + 1], v2 * bfh(w2));
    atomicAdd(&acc[a3], v3 * bfu(w3)); atomicAdd(&acc[a3 + 1], v3 * bfh(w3));
  }
  for (; i < s1; i += 128) {
    int2 e = bp[i];
    unsigned int w = fb16[(size_t)(e.x & 0x3FFFFF) * 8 + f2];
    float v = __int_as_float(e.y);
    int a = ((unsigned)e.x >> 22) * 17 + 2 * f2;
    atomicAdd(&acc[a], v * bfu(w));
    atomicAdd(&acc[a + 1], v * bfh(w));
  }
  __syncthreads();
  int r0 = b * RPB;
  int nr = min(RPB, Nn - r0);
  if (nr > 0)
    for (int j = t; j < nr * 16; j += 1024)
      pm_y[(size_t)r0 * 16 + j] = acc[(j >> 4) * 17 + (j & 15)];
}

// ---------------------------------------------------------------------------
// pm over one bucket, fp32 feat_b fallback (small-ws path).
// ---------------------------------------------------------------------------
__global__ __launch_bounds__(1024) void pm_bucket_f32(
    const float* __restrict__ feat_b, const int2* __restrict__ bp,
    const int* __restrict__ bs, float* __restrict__ pm_y) {
  __shared__ float acc[RPB * 17];
  int t = threadIdx.x;
  int b = blockIdx.x;
  for (int i = t; i < RPB * 17; i += 1024) acc[i] = 0.f;
  __syncthreads();
  int s0 = bs[b], s1 = bs[b + 1];
  int g = t >> 4, f = t & 15;
  int i = s0 + g;
  for (; i + 192 < s1; i += 256) {
    int2 e0 = bp[i];
    int2 e1 = bp[i + 64];
    int2 e2 = bp[i + 128];
    int2 e3 = bp[i + 192];
    float x0 = feat_b[(size_t)(e0.x & 0x3FFFFF) * 16 + f];
    float x1 = feat_b[(size_t)(e1.x & 0x3FFFFF) * 16 + f];
    float x2 = feat_b[(size_t)(e2.x & 0x3FFFFF) * 16 + f];
    float x3 = feat_b[(size_t)(e3.x & 0x3FFFFF) * 16 + f];
    atomicAdd(&acc[((unsigned)e0.x >> 22) * 17 + f], __int_as_float(e0.y) * x0);
    atomicAdd(&acc[((unsigned)e1.x >> 22) * 17 + f], __int_as_float(e1.y) * x1);
    atomicAdd(&acc[((unsigned)e2.x >> 22) * 17 + f], __int_as_float(e2.y) * x2);
    atomicAdd(&acc[((unsigned)e3.x >> 22) * 17 + f], __int_as_float(e3.y) * x3);
  }
  for (; i < s1; i += 64) {
    int2 e = bp[i];
    atomicAdd(&acc[((unsigned)e.x >> 22) * 17 + f],
              __int_as_float(e.y) * feat_b[(size_t)(e.x & 0x3FFFFF) * 16 + f]);
  }
  __syncthreads();
  int r0 = b * RPB;
  int nr = min(RPB, Nn - r0);
  if (nr > 0)
    for (int j = t; j < nr * 16; j += 1024)
      pm_y[(size_t)r0 * 16 + j] = acc[(j >> 4) * 17 + (j & 15)];
}

// ---------------------------------------------------------------------------
// Fused per-node projections + ReLU(second half) + BN-stat partial reduction.
// z1,z2,z4 are bf16 uint-packed.
// ---------------------------------------------------------------------------
__global__ __launch_bounds__(256) void fuse_kernel(
    const float* __restrict__ feat_a, const float* __restrict__ deg,
    const unsigned int* __restrict__ z1, const unsigned int* __restrict__ z2,
    const unsigned int* __restrict__ z4, const float* __restrict__ pmy,
    const float* __restrict__ Wprev, const float* __restrict__ bprev,
    const float* __restrict__ Wdeg,  const float* __restrict__ bdeg,
    const float* __restrict__ Wrad,  const float* __restrict__ brad,
    const float* __restrict__ Wfuse, const float* __restrict__ bfuse,
    float* __restrict__ result, float* __restrict__ stats) {
  __shared__ float sWp[256], sWd[256], sWr[768], sWf[256], sB[16];
  int t = threadIdx.x;
  sWp[t] = Wprev[t];
  sWd[t] = Wdeg[t];
  sWf[t] = Wfuse[t];
  for (int i = t; i < 768; i += 256) sWr[i] = Wrad[i];
  if (t < 16)
    sB[t] = bprev[t] + bdeg[t] + brad[t] + brad[16 + t] + brad[32 + t] + bfuse[t];
  __syncthreads();

  int n = blockIdx.x * 256 + t;
  bool valid = n < Nn;

  float fa[16], a1[16], a2[16], a4[16], py[16];
  float dg = 0.f;
  if (valid) {
    const float4* p;
    p = (const float4*)(feat_a + (size_t)n * 16);
    ((float4*)fa)[0] = p[0]; ((float4*)fa)[1] = p[1];
    ((float4*)fa)[2] = p[2]; ((float4*)fa)[3] = p[3];
    p = (const float4*)(pmy + (size_t)n * 16);
    ((float4*)py)[0] = p[0]; ((float4*)py)[1] = p[1];
    ((float4*)py)[2] = p[2]; ((float4*)py)[3] = p[3];
#pragma unroll
    for (int k = 0; k < 8; k++) {
      unsigned int w1 = z1[(size_t)n * 8 + k];
      unsigned int w2 = z2[(size_t)n * 8 + k];
      unsigned int w4 = z4[(size_t)n * 8 + k];
      a1[2 * k] = bfu(w1); a1[2 * k + 1] = bfh(w1);
      a2[2 * k] = bfu(w2); a2[2 * k + 1] = bfh(w2);
      a4[2 * k] = bfu(w4); a4[2 * k + 1] = bfh(w4);
    }
    dg = deg[n];
  } else {
#pragma unroll
    for (int i = 0; i < 16; i++) { fa[i] = a1[i] = a2[i] = a4[i] = py[i] = 0.f; }
  }

  float out[16];
#pragma unroll
  for (int o = 0; o < 16; o++) {
    float a = sB[o];
#pragma unroll
    for (int i = 0; i < 16; i++) {
      a += fa[i] * (sWp[i * 16 + o] + dg * sWd[i * 16 + o]);
      a += a1[i] * sWr[i * 16 + o];
      a += a2[i] * sWr[256 + i * 16 + o];
      a += a4[i] * sWr[512 + i * 16 + o];
      a += py[i] * sWf[i * 16 + o];
    }
    out[o] = (o >= 8) ? fmaxf(a, 0.f) : a;
  }

  if (valid) {
    float4* r = (float4*)(result + (size_t)n * 16);
    r[0] = ((float4*)out)[0]; r[1] = ((float4*)out)[1];
    r[2] = ((float4*)out)[2]; r[3] = ((float4*)out)[3];
  } else {
#pragma unroll
    for (int o = 0; o < 16; o++) out[o] = 0.f;
  }

#pragma unroll
  for (int o = 0; o < 16; o++) {
    float s = out[o];
    float q = out[o] * out[o];
#pragma unroll
    for (int m = 32; m >= 1; m >>= 1) {
      s += __shfl_xor(s, m, 64);
      q += __shfl_xor(q, m, 64);
    }
    if ((t & 63) == 0) {
      atomicAdd(&stats[o], s);
      atomicAdd(&stats[16 + o], q);
    }
  }
}

// ---------------------------------------------------------------------------
__global__ void bn_coeffs(float* __restrict__ stats,
                          const float* __restrict__ gamma,
                          const float* __restrict__ beta) {
  int t = threadIdx.x;
  if (t < 16) {
    float mean = stats[t] * (1.0f / Nn);
    float var  = stats[16 + t] * (1.0f / Nn) - mean * mean;
    float sc   = gamma[t] * rsqrtf(var + 1e-5f);
    stats[32 + t] = sc;
    stats[48 + t] = beta[t] - mean * sc;
  }
}

__global__ __launch_bounds__(256) void bn_apply(
    float* __restrict__ result, const float* __restrict__ stats) {
  int idx = blockIdx.x * 256 + threadIdx.x;          // over Nn*4
  if (idx >= Nn * 4) return;
  int c = (idx & 3) * 4;
  float4 r = ((const float4*)result)[idx];
  float4 o;
  o.x = r.x * stats[32 + c + 0] + stats[48 + c + 0];
  o.y = r.y * stats[32 + c + 1] + stats[48 + c + 1];
  o.z = r.z * stats[32 + c + 2] + stats[48 + c + 2];
  o.w = r.w * stats[32 + c + 3] + stats[48 + c + 3];
  ((float4*)result)[idx] = o;
}

// ---------------------------------------------------------------------------
extern "C" void kernel_launch(void* const* d_in, const int* in_sizes, int n_in,
                              void* d_out, int out_size, void* d_ws, size_t ws_size,
                              hipStream_t stream) {
  const float* feat_a  = (const float*)d_in[0];
  const float* feat_b  = (const float*)d_in[1];
  const float* deg     = (const float*)d_in[2];
  const float* pm_vals = (const float*)d_in[3];
  const float* W_prev  = (const float*)d_in[4];
  const float* b_prev  = (const float*)d_in[5];
  const float* W_deg   = (const float*)d_in[6];
  const float* b_deg   = (const float*)d_in[7];
  const float* W_rad   = (const float*)d_in[8];
  const float* b_rad   = (const float*)d_in[9];
  const float* W_fuse  = (const float*)d_in[10];
  const float* b_fuse  = (const float*)d_in[11];
  const float* bn_g    = (const float*)d_in[12];
  const float* bn_b    = (const float*)d_in[13];
  const int*   src     = (const int*)d_in[14];
  const int*   dst     = (const int*)d_in[15];
  const int*   pm_rows = (const int*)d_in[16];
  const int*   pm_cols = (const int*)d_in[17];

  char* wsb = (char*)d_ws;
  int*  binned_e = (int*)wsb;                               // Ee ints (12.8 MB)
  int2* bp       = (int2*)(wsb + (size_t)Ee * 4);           // NNZn int2 (51.2 MB)
  float* pm_y    = (float*)(wsb + (size_t)Ee * 4 + (size_t)NNZn * 8);  // NF
  int* tab   = (int*)((char*)pm_y + (size_t)NF * 4);
  int* tot_e = tab;               // K
  int* tot_p = tab + K;           // K
  int* bs_e  = tab + 2 * K;       // K+1
  int* cur_e = tab + 3 * K + 1;   // K
  int* bs_p  = tab + 4 * K + 1;   // K+1
  int* cur_p = tab + 5 * K + 2;   // K
  float* stats = (float*)(tab + 6 * K + 2);  // 64
  char* after_tab = (char*)(tab + 6 * K + 2 + 64);
  // bf16 feat_b (optional, 102.4 MB), 256-byte aligned
  size_t fb_off = (((size_t)(after_tab - wsb)) + 255) & ~(size_t)255;
  unsigned int* fb16 = (unsigned int*)(wsb + fb_off);
  bool use_fb16 = (ws_size >= fb_off + (size_t)Ee * 16 * 2);

  // bf16 z buffers + fa16 alias the bp region (dead after pm_bucket):
  // 5 * Nn*16*2 B = 16 MB <= 51.2 MB
  unsigned int* fa16 = (unsigned int*)bp;                   // Nn*8 uints
  unsigned int* z1 = fa16 + (size_t)Nn * 8;
  unsigned int* z2 = z1 + (size_t)Nn * 8;
  unsigned int* z3 = z2 + (size_t)Nn * 8;
  unsigned int* z4 = z3 + (size_t)Nn * 8;
  float* result = (float*)d_out;

  // zero bucket totals + stats
  hipMemsetAsync(tab, 0, (size_t)(6 * K + 2 + 64) * sizeof(int), stream);

  int cb_e = (Ee + CHUNK - 1) / CHUNK;     // 196
  int cb_p = (NNZn + CHUNK - 1) / CHUNK;   // 391
  count_kernel<<<cb_e, 256, 0, stream>>>(dst, Ee, tot_e);
  count_kernel<<<cb_p, 256, 0, stream>>>(pm_rows, NNZn, tot_p);
  scan_kernel<<<2, K, 0, stream>>>(tot_e, tot_p, bs_e, cur_e, bs_p, cur_p);
  bin_edges<<<cb_e, 256, 0, stream>>>(dst, src, cur_e, binned_e);
  bin_pm<<<cb_p, 256, 0, stream>>>(pm_rows, pm_cols, pm_vals, cur_p, bp);

  // pm first: consumes bp, freeing it for fa16/z1..z4
  if (use_fb16) {
    int cvb = ((Ee * 8) + 255) / 256;      // Ee*16/2 pairs
    cvt_bf16<<<cvb, 256, 0, stream>>>(feat_b, fb16, Ee * 8);
    pm_bucket_bf<<<K, 1024, 0, stream>>>(fb16, bp, bs_p, pm_y);
  } else {
    pm_bucket_f32<<<K, 1024, 0, stream>>>(feat_b, bp, bs_p, pm_y);
  }

  // convert feat_a to bf16, then 4 L2-resident hops
  int cva = ((Nn * 8) + 255) / 256;
  cvt_bf16<<<cva, 256, 0, stream>>>(feat_a, fa16, Nn * 8);
  hop_bucket<<<K, 1024, 0, stream>>>(fa16, z1, binned_e, bs_e);
  hop_bucket<<<K, 1024, 0, stream>>>(z1, z2, binned_e, bs_e);
  hop_bucket<<<K, 1024, 0, stream>>>(z2, z3, binned_e, bs_e);
  hop_bucket<<<K, 1024, 0, stream>>>(z3, z4, binned_e, bs_e);

  int fuse_blocks = (Nn + 255) / 256;
  fuse_kernel<<<fuse_blocks, 256, 0, stream>>>(
      feat_a, deg, z1, z2, z4, pm_y,
      W_prev, b_prev, W_deg, b_deg, W_rad, b_rad, W_fuse, b_fuse,
      result, stats);

  bn_coeffs<<<1, 64, 0, stream>>>(stats, bn_g, bn_b);

  int bn_blocks = (Nn * 4 + 255) / 256;
  bn_apply<<<bn_blocks, 256, 0, stream>>>(result, stats);
}